// Round 1
// baseline (142.804 us; speedup 1.0000x reference)
//
#include <hip/hip_runtime.h>

#define BATCH 131072
#define IN 128
#define OUT 128
#define PNUM 16

typedef _Float16 f16x8 __attribute__((ext_vector_type(8)));
typedef float f32x4 __attribute__((ext_vector_type(4)));

// tanh(v) = 1 - 2/(exp(2v)+1); exact at +/-inf saturation, ~1e-7 rel error,
// far below f16 rounding (5e-4).
__device__ __forceinline__ float tanh_fast(float v) {
    float e = __expf(2.0f * v);
    return 1.0f - 2.0f * __builtin_amdgcn_rcpf(e + 1.0f);
}

// w[o*IN + i] = (f16) sum_p coef[o][i][p]   (16384 outputs, one thread each;
// each thread reads 64B contiguous -> coalesced float4 x4)
__global__ __launch_bounds__(256) void prep_w_kernel(const float* __restrict__ coef,
                                                     _Float16* __restrict__ w) {
    int t = blockIdx.x * blockDim.x + threadIdx.x;
    const float4* p = (const float4*)(coef + (size_t)t * PNUM);
    float4 a = p[0], b = p[1], c = p[2], d = p[3];
    float s = (a.x + a.y + a.z + a.w) + (b.x + b.y + b.z + b.w)
            + (c.x + c.y + c.z + c.w) + (d.x + d.y + d.z + d.w);
    w[t] = (_Float16)s;
}

// Each wave: 16 rows of x, all 128 output cols.
// A-frag (16x16x32 f16): lane holds A[m = lane&15][k = (lane>>4)*8 + j]
// B-frag:                lane holds B[k = (lane>>4)*8 + j][n = lane&15] = w[n][k]
// C/D:                   out[row = (lane>>4)*4 + r][col = lane&15]
__global__ __launch_bounds__(256) void gemm_tanh_kernel(const float* __restrict__ x,
                                                        const _Float16* __restrict__ w,
                                                        const float* __restrict__ trange,
                                                        float* __restrict__ out) {
    const float t = trange[0];
    const int lane = threadIdx.x & 63;
    const int wv   = threadIdx.x >> 6;
    const int m = lane & 15;
    const int q = lane >> 4;

    const size_t row_base = (size_t)blockIdx.x * 64 + (size_t)wv * 16;
    const float* xrow = x + (row_base + m) * IN;

    f32x4 acc[8];
#pragma unroll
    for (int nt = 0; nt < 8; ++nt) acc[nt] = (f32x4){0.f, 0.f, 0.f, 0.f};

#pragma unroll
    for (int ks = 0; ks < 4; ++ks) {
        const int k0 = ks * 32 + q * 8;
        float4 xa = *(const float4*)(xrow + k0);
        float4 xb = *(const float4*)(xrow + k0 + 4);
        f16x8 afrag;
        afrag[0] = (_Float16)tanh_fast(xa.x * t);
        afrag[1] = (_Float16)tanh_fast(xa.y * t);
        afrag[2] = (_Float16)tanh_fast(xa.z * t);
        afrag[3] = (_Float16)tanh_fast(xa.w * t);
        afrag[4] = (_Float16)tanh_fast(xb.x * t);
        afrag[5] = (_Float16)tanh_fast(xb.y * t);
        afrag[6] = (_Float16)tanh_fast(xb.z * t);
        afrag[7] = (_Float16)tanh_fast(xb.w * t);
#pragma unroll
        for (int nt = 0; nt < 8; ++nt) {
            f16x8 bfrag = *(const f16x8*)(w + (size_t)(nt * 16 + m) * IN + k0);
            acc[nt] = __builtin_amdgcn_mfma_f32_16x16x32_f16(afrag, bfrag, acc[nt], 0, 0, 0);
        }
    }

    float* orow = out + (row_base + q * 4) * OUT + m;
#pragma unroll
    for (int nt = 0; nt < 8; ++nt) {
#pragma unroll
        for (int r = 0; r < 4; ++r) {
            orow[(size_t)r * OUT + nt * 16] = acc[nt][r];
        }
    }
}

extern "C" void kernel_launch(void* const* d_in, const int* in_sizes, int n_in,
                              void* d_out, int out_size, void* d_ws, size_t ws_size,
                              hipStream_t stream) {
    const float* x    = (const float*)d_in[0];
    const float* coef = (const float*)d_in[1];
    const float* tr   = (const float*)d_in[2];
    float* out = (float*)d_out;
    _Float16* w = (_Float16*)d_ws;   // 128*128*2 = 32 KB scratch

    prep_w_kernel<<<(OUT * IN) / 256, 256, 0, stream>>>(coef, w);
    gemm_tanh_kernel<<<BATCH / 64, 256, 0, stream>>>(x, w, tr, out);
}

// Round 2
// 119.465 us; speedup vs baseline: 1.1954x; 1.1954x over previous
//
#include <hip/hip_runtime.h>

#define BATCH 131072
#define IN 128
#define OUT 128
#define PNUM 16
#define LDS_PITCH 136   // 128 + 8 f16 pad: ds_read_b128 lanes land 2-way max (free)

typedef _Float16 f16x8 __attribute__((ext_vector_type(8)));
typedef float f32x4 __attribute__((ext_vector_type(4)));

__device__ __forceinline__ float tanh_fast(float v) {
    float e = __expf(2.0f * v);
    return 1.0f - 2.0f * __builtin_amdgcn_rcpf(e + 1.0f);
}

// w[o*IN + i] = (f16) sum_p coef[o][i][p]
__global__ __launch_bounds__(256) void prep_w_kernel(const float* __restrict__ coef,
                                                     _Float16* __restrict__ w) {
    int t = blockIdx.x * blockDim.x + threadIdx.x;
    const float4* p = (const float4*)(coef + (size_t)t * PNUM);
    float4 a = p[0], b = p[1], c = p[2], d = p[3];
    float s = (a.x + a.y + a.z + a.w) + (b.x + b.y + b.z + b.w)
            + (c.x + c.y + c.z + c.w) + (d.x + d.y + d.z + d.w);
    w[t] = (_Float16)s;
}

// Block = 512 threads (8 waves), each wave: 16 rows x 128 cols.
// w staged to LDS once per block; all 8 x-loads issued before the barrier.
__global__ __launch_bounds__(512, 5) void gemm_tanh_kernel(const float* __restrict__ x,
                                                           const _Float16* __restrict__ w,
                                                           const float* __restrict__ trange,
                                                           float* __restrict__ out) {
    __shared__ _Float16 wlds[OUT * LDS_PITCH];

    const float t = trange[0];
    const int tid  = threadIdx.x;
    const int lane = tid & 63;
    const int wv   = tid >> 6;        // 0..7
    const int m = lane & 15;
    const int q = lane >> 4;

    const size_t row_base = (size_t)blockIdx.x * 128 + (size_t)wv * 16;
    const float* xrow = x + (row_base + m) * IN;

    // 1. issue the full x row for this lane (8 independent dwordx4 -> max MLP)
    float4 xv[8];
#pragma unroll
    for (int ks = 0; ks < 4; ++ks) {
        xv[2 * ks]     = *(const float4*)(xrow + ks * 32 + q * 8);
        xv[2 * ks + 1] = *(const float4*)(xrow + ks * 32 + q * 8 + 4);
    }

    // 2. cooperative stage of w (32 KB, L2-resident) into padded LDS
#pragma unroll
    for (int i = 0; i < 4; ++i) {
        int idx = (i * 512 + tid) * 8;          // f16 index, 8 per thread per pass
        int r = idx >> 7;
        int c = idx & 127;
        *(f16x8*)&wlds[r * LDS_PITCH + c] = *(const f16x8*)(w + idx);
    }
    __syncthreads();

    // 3. tanh + cvt -> A fragments (x loads have drained at the barrier)
    f16x8 af[4];
#pragma unroll
    for (int ks = 0; ks < 4; ++ks) {
        float4 a = xv[2 * ks], b = xv[2 * ks + 1];
        af[ks][0] = (_Float16)tanh_fast(a.x * t);
        af[ks][1] = (_Float16)tanh_fast(a.y * t);
        af[ks][2] = (_Float16)tanh_fast(a.z * t);
        af[ks][3] = (_Float16)tanh_fast(a.w * t);
        af[ks][4] = (_Float16)tanh_fast(b.x * t);
        af[ks][5] = (_Float16)tanh_fast(b.y * t);
        af[ks][6] = (_Float16)tanh_fast(b.z * t);
        af[ks][7] = (_Float16)tanh_fast(b.w * t);
    }

    // 4. MFMA over all 8 col-tiles, B from LDS
    f32x4 acc[8];
#pragma unroll
    for (int nt = 0; nt < 8; ++nt) acc[nt] = (f32x4){0.f, 0.f, 0.f, 0.f};

#pragma unroll
    for (int ks = 0; ks < 4; ++ks) {
        const int kb = ks * 32 + q * 8;
#pragma unroll
        for (int nt = 0; nt < 8; ++nt) {
            f16x8 bf = *(const f16x8*)&wlds[(nt * 16 + m) * LDS_PITCH + kb];
            acc[nt] = __builtin_amdgcn_mfma_f32_16x16x32_f16(af[ks], bf, acc[nt], 0, 0, 0);
        }
    }

    // 5. store: quarter-wave writes 16 contiguous floats per (nt, r)
    float* orow = out + (row_base + q * 4) * OUT + m;
#pragma unroll
    for (int nt = 0; nt < 8; ++nt) {
#pragma unroll
        for (int r = 0; r < 4; ++r) {
            orow[(size_t)r * OUT + nt * 16] = acc[nt][r];
        }
    }
}

extern "C" void kernel_launch(void* const* d_in, const int* in_sizes, int n_in,
                              void* d_out, int out_size, void* d_ws, size_t ws_size,
                              hipStream_t stream) {
    const float* x    = (const float*)d_in[0];
    const float* coef = (const float*)d_in[1];
    const float* tr   = (const float*)d_in[2];
    float* out = (float*)d_out;
    _Float16* w = (_Float16*)d_ws;   // 32 KB scratch

    prep_w_kernel<<<(OUT * IN) / 256, 256, 0, stream>>>(coef, w);
    gemm_tanh_kernel<<<BATCH / 128, 512, 0, stream>>>(x, w, tr, out);
}